// Round 1
// 360.020 us; speedup vs baseline: 1.1442x; 1.1442x over previous
//
#include <hip/hip_runtime.h>

// Problem constants
#define B_   32
#define CIN  256
#define H_   64
#define W_   64
#define COUT 512
#define G_   9
#define CPG_IN  28          // 252 used input channels / 9 groups
#define HW_  (H_*W_)        // 4096
#define HW4_ (HW_/4)        // 1024 float4 per plane

// Padded s' geometry: padded coord = real + 1; halo (zeros) removes ALL bounds
// checks in kernel C. Row stride 68 floats = 272 B (16B-aligned); plane
// 66*68*4 = 17952 B (16B-aligned). C's f4 loads land on 16B boundaries.
#define HP 66
#define WP 68
#define PLANE (HP*WP)        // 4488 floats
#define VSTRIDE 16           // v padded to [512][16] for aligned scalar loads

typedef float f4 __attribute__((ext_vector_type(4)));

// ---------------------------------------------------------------------------
// Kernel A: v[o][g] = sum of w_pw[o, c] over group g's columns.
// g = c/56 for c < 504; c in [504,512) folds into centre group 4.
// One block (64 threads) per o; per-group wave shuffle reduction, no atomics.
// ---------------------------------------------------------------------------
__global__ __launch_bounds__(64) void reduce_w_kernel(const float* __restrict__ w,
                                                      float* __restrict__ v) {
    const int o = blockIdx.x;
    const int t = threadIdx.x;          // 0..63
    const float* row = w + o * COUT;
#pragma unroll
    for (int g = 0; g < G_; ++g) {
        float val = (t < 56) ? row[g * 56 + t] : 0.0f;
        if (g == 4 && t >= 56) val = row[504 + (t - 56)];   // miss channels -> centre
#pragma unroll
        for (int off = 32; off; off >>= 1) val += __shfl_down(val, off);
        if (t == 0) v[o * VSTRIDE + g] = val;
    }
}

// ---------------------------------------------------------------------------
// Kernel B: s'[b][g][h+1][w+1] = sum_{k<28} x[b][28g+k][h][w]  (+ halo zeroing)
// x is touch-once -> nontemporal loads; s' must stay L2/L3-resident -> normal
// stores. Interior stores are scalar (dest is +1-shifted, not 16B-aligned).
// Blocks >= NMAIN zero the halo of one (b,g) plane each (re-poisoned each run).
// ---------------------------------------------------------------------------
#define NMAIN (B_*G_*HW4_/256)   // 1152 main blocks
__global__ __launch_bounds__(256) void group_sum_kernel(const float* __restrict__ x,
                                                        float* __restrict__ s) {
    const int bid = blockIdx.x;
    const int tid = threadIdx.x;
    if (bid < NMAIN) {
        const int idx = bid * 256 + tid;   // float4 units; total B*9*1024
        const int m  = idx & (HW4_ - 1);
        const int gb = idx >> 10;          // b*9 + g
        const int g  = gb % G_;
        const int b  = gb / G_;
        const int hh = m >> 4;             // row 0..63
        const int ww = (m & 15) * 4;       // col 0..60 step 4
        const f4* xp = (const f4*)x;
        long base = ((long)(b * CIN + g * CPG_IN)) * HW4_ + m;
        f4 acc = (f4)0.0f;
#pragma unroll
        for (int k = 0; k < CPG_IN; ++k) {
            acc += __builtin_nontemporal_load(xp + base + (long)k * HW4_);
        }
        float* sp = s + (long)gb * PLANE + (hh + 1) * WP + (ww + 1);
        sp[0] = acc.x; sp[1] = acc.y; sp[2] = acc.z; sp[3] = acc.w;
    } else {
        // Halo zeroing: rows 0 & 65 full width; cols {0,65,66,67} for rows 1..64.
        const int plane = bid - NMAIN;       // 0..287 = b*9+g
        float* sp = s + (long)plane * PLANE;
#pragma unroll
        for (int pass = 0; pass < 2; ++pass) {
            int i = tid + pass * 256;
            if (i < 392) {
                int p;
                if (i < 68)       p = i;                       // top row
                else if (i < 136) p = 65 * WP + (i - 68);      // bottom row
                else {
                    int k = i - 136;                           // 0..255
                    int r = 1 + (k >> 2);                      // rows 1..64
                    int c = k & 3;                             // 0->col0, 1..3->65..67
                    p = r * WP + (c == 0 ? 0 : 64 + c);
                }
                sp[p] = 0.0f;
            }
        }
    }
}

// ---------------------------------------------------------------------------
// Kernel C: out[b][o][h][w] = sum_g v[o][g] * s'[b][g][h+g/3][w+g%3] (padded)
// NO LDS, NO barrier, NO bounds checks: per thread, 18 aligned f4 loads from
// the L2/L3-resident padded s' (9 planes x 8 cols covering all three gj
// shifts), then oi-OUTER loop: 4-reg accumulator, one NT store per output
// plane. LDS reuse in the old version was 0.86 (<1) -- staging was overhead.
// Occupancy: no LDS; __launch_bounds__(256,4) caps VGPR<=128 -> 16 waves/CU
// (was 12, LDS-capped).
// ---------------------------------------------------------------------------
#define O_TILE 16
#define H_TILE 16

__global__ __launch_bounds__(256, 4) void shift_pw_kernel(const float* __restrict__ s,
                                                          const float* __restrict__ v,
                                                          float* __restrict__ out) {
    const int bid = blockIdx.x;
    const int ot  = bid & 31;         // 32 o-tiles
    const int ht  = (bid >> 5) & 3;   // 4 h-tiles
    const int b   = bid >> 7;         // 32 batches
    const int h0  = ht * H_TILE;
    const int tid = threadIdx.x;
    const int o0  = ot * O_TILE;
    const int w0  = (tid & 15) * 4;   // 16 float4-columns cover W=64
    const int hl  = tid >> 4;         // 16 rows

    // Preload oi-invariant s-values: per g, padded row h0+hl+g/3, cols w0..w0+7.
    // All loads 16B-aligned (row stride 272B, w0*4 multiple of 16).
    const float* sb = s + (long)b * G_ * PLANE;
    f4 sa[G_], sbv[G_];
#pragma unroll
    for (int g = 0; g < G_; ++g) {
        const int gi = g / 3;
        const float* rp = sb + g * PLANE + (h0 + hl + gi) * WP + w0;
        sa[g]  = *(const f4*)rp;
        sbv[g] = *(const f4*)(rp + 4);
    }

    long obase = (((long)b * COUT + o0) * H_ + (h0 + hl)) * W_ + w0;
    const float* vp = v + o0 * VSTRIDE;   // block-uniform -> scalar loads
#pragma unroll
    for (int oi = 0; oi < O_TILE; ++oi) {
        f4 acc = (f4)0.0f;
#pragma unroll
        for (int g = 0; g < G_; ++g) {
            const int gj = g - (g / 3) * 3;
            const float vv = vp[oi * VSTRIDE + g];
            float s0, s1, s2, s3;
            if (gj == 0)      { s0 = sa[g].x; s1 = sa[g].y; s2 = sa[g].z; s3 = sa[g].w; }
            else if (gj == 1) { s0 = sa[g].y; s1 = sa[g].z; s2 = sa[g].w; s3 = sbv[g].x; }
            else              { s0 = sa[g].z; s1 = sa[g].w; s2 = sbv[g].x; s3 = sbv[g].y; }
            acc.x += vv * s0;
            acc.y += vv * s1;
            acc.z += vv * s2;
            acc.w += vv * s3;
        }
        // out is touch-once -> nontemporal; each wave's store = 1 KiB contiguous
        __builtin_nontemporal_store(acc, (f4*)(out + obase + (long)oi * HW_));
    }
}

// ---------------------------------------------------------------------------
extern "C" void kernel_launch(void* const* d_in, const int* in_sizes, int n_in,
                              void* d_out, int out_size, void* d_ws, size_t ws_size,
                              hipStream_t stream) {
    const float* x    = (const float*)d_in[0];   // (32,256,64,64) fp32
    const float* w_pw = (const float*)d_in[1];   // (512,512) fp32
    float* out = (float*)d_out;                  // (32,512,64,64) fp32

    // workspace layout: v[512][16] at 0 (32 KiB exactly), padded s' at 32 KiB
    // (32*9*4488 floats = 5.17 MiB)
    float* v = (float*)d_ws;
    float* s = (float*)((char*)d_ws + 32768);

    // A: w reduction -> v[512][16]
    reduce_w_kernel<<<COUT, 64, 0, stream>>>(w_pw, v);

    // B: x group sum -> padded s' (+ 288 halo-zeroing blocks)
    group_sum_kernel<<<NMAIN + B_ * G_, 256, 0, stream>>>(x, s);

    // C: main shifted pointwise, LDS-free
    shift_pw_kernel<<<B_ * (H_ / H_TILE) * (COUT / O_TILE), 256, 0, stream>>>(s, v, out);
}

// Round 2
// 358.583 us; speedup vs baseline: 1.1488x; 1.0040x over previous
//
#include <hip/hip_runtime.h>

// Problem constants
#define B_   32
#define CIN  256
#define H_   64
#define W_   64
#define COUT 512
#define G_   9
#define CPG_IN  28          // 252 used input channels / 9 groups
#define HW_  (H_*W_)        // 4096
#define HW4_ (HW_/4)        // 1024 float4 per plane

// Padded s' geometry: padded coord = real + 1; halo (zeros) removes ALL bounds
// checks in kernel C. Row stride 68 floats = 272 B (16B-aligned); plane
// 66*68*4 = 17952 B (16B-aligned). C's f4 loads land on 16B boundaries.
#define HP 66
#define WP 68
#define PLANE (HP*WP)        // 4488 floats
#define VSTRIDE 16           // v padded to [512][16] for aligned scalar loads

typedef float f4 __attribute__((ext_vector_type(4)));

// ---------------------------------------------------------------------------
// Kernel A: v[o][g] = sum of w_pw[o, c] over group g's columns.
// g = c/56 for c < 504; c in [504,512) folds into centre group 4.
// One block (64 threads) per o; per-group wave shuffle reduction, no atomics.
// ---------------------------------------------------------------------------
__global__ __launch_bounds__(64) void reduce_w_kernel(const float* __restrict__ w,
                                                      float* __restrict__ v) {
    const int o = blockIdx.x;
    const int t = threadIdx.x;          // 0..63
    const float* row = w + o * COUT;
#pragma unroll
    for (int g = 0; g < G_; ++g) {
        float val = (t < 56) ? row[g * 56 + t] : 0.0f;
        if (g == 4 && t >= 56) val = row[504 + (t - 56)];   // miss channels -> centre
#pragma unroll
        for (int off = 32; off; off >>= 1) val += __shfl_down(val, off);
        if (t == 0) v[o * VSTRIDE + g] = val;
    }
}

// ---------------------------------------------------------------------------
// Kernel B: s'[b][g][h+1][w+1] = sum_{k<28} x[b][28g+k][h][w]  (+ halo zeroing)
// x is touch-once -> nontemporal loads; s' must stay L2/L3-resident -> normal
// stores. Interior stores are scalar (dest is +1-shifted, not 16B-aligned).
// Blocks >= NMAIN zero the halo of one (b,g) plane each (re-poisoned each run).
// ---------------------------------------------------------------------------
#define NMAIN (B_*G_*HW4_/256)   // 1152 main blocks
__global__ __launch_bounds__(256) void group_sum_kernel(const float* __restrict__ x,
                                                        float* __restrict__ s) {
    const int bid = blockIdx.x;
    const int tid = threadIdx.x;
    if (bid < NMAIN) {
        const int idx = bid * 256 + tid;   // float4 units; total B*9*1024
        const int m  = idx & (HW4_ - 1);
        const int gb = idx >> 10;          // b*9 + g
        const int g  = gb % G_;
        const int b  = gb / G_;
        const int hh = m >> 4;             // row 0..63
        const int ww = (m & 15) * 4;       // col 0..60 step 4
        const f4* xp = (const f4*)x;
        long base = ((long)(b * CIN + g * CPG_IN)) * HW4_ + m;
        f4 acc = (f4)0.0f;
#pragma unroll
        for (int k = 0; k < CPG_IN; ++k) {
            acc += __builtin_nontemporal_load(xp + base + (long)k * HW4_);
        }
        float* sp = s + (long)gb * PLANE + (hh + 1) * WP + (ww + 1);
        sp[0] = acc.x; sp[1] = acc.y; sp[2] = acc.z; sp[3] = acc.w;
    } else {
        // Halo zeroing: rows 0 & 65 full width; cols {0,65,66,67} for rows 1..64.
        const int plane = bid - NMAIN;       // 0..287 = b*9+g
        float* sp = s + (long)plane * PLANE;
#pragma unroll
        for (int pass = 0; pass < 2; ++pass) {
            int i = tid + pass * 256;
            if (i < 392) {
                int p;
                if (i < 68)       p = i;                       // top row
                else if (i < 136) p = 65 * WP + (i - 68);      // bottom row
                else {
                    int k = i - 136;                           // 0..255
                    int r = 1 + (k >> 2);                      // rows 1..64
                    int c = k & 3;                             // 0->col0, 1..3->65..67
                    p = r * WP + (c == 0 ? 0 : 64 + c);
                }
                sp[p] = 0.0f;
            }
        }
    }
}

// ---------------------------------------------------------------------------
// Kernel C: out[b][o][h][w] = sum_g v[o][g] * s'[b][g][h+g/3][w+g%3] (padded)
// NO LDS, NO barrier, NO bounds checks: per thread, 18 aligned f4 loads from
// the L2/L3-resident padded s' (9 planes x 8 cols covering all three gj
// shifts), then oi-OUTER loop: 4-reg accumulator, one NT store per output
// plane. O_TILE=32 (was 16): same 18 preloads now amortized over 32 output
// planes -> s' L3->L2 read traffic halves (~300->~150 MB), removing the read
// stream competing with the 268 MB NT store stream (store-bound steady state:
// 36 FMA = 72 SIMD-cyc vs 1 KiB/wave store ~= 96 CU-cyc). VGPR ~95 < 128 ->
// still 16 waves/CU with __launch_bounds__(256,4).
// ---------------------------------------------------------------------------
#define O_TILE 32
#define H_TILE 16

__global__ __launch_bounds__(256, 4) void shift_pw_kernel(const float* __restrict__ s,
                                                          const float* __restrict__ v,
                                                          float* __restrict__ out) {
    const int bid = blockIdx.x;
    const int ot  = bid & 15;         // 16 o-tiles
    const int ht  = (bid >> 4) & 3;   // 4 h-tiles
    const int b   = bid >> 6;         // 32 batches
    const int h0  = ht * H_TILE;
    const int tid = threadIdx.x;
    const int o0  = ot * O_TILE;
    const int w0  = (tid & 15) * 4;   // 16 float4-columns cover W=64
    const int hl  = tid >> 4;         // 16 rows

    // Preload oi-invariant s-values: per g, padded row h0+hl+g/3, cols w0..w0+7.
    // All loads 16B-aligned (row stride 272B, w0*4 multiple of 16).
    const float* sb = s + (long)b * G_ * PLANE;
    f4 sa[G_], sbv[G_];
#pragma unroll
    for (int g = 0; g < G_; ++g) {
        const int gi = g / 3;
        const float* rp = sb + g * PLANE + (h0 + hl + gi) * WP + w0;
        sa[g]  = *(const f4*)rp;
        sbv[g] = *(const f4*)(rp + 4);
    }

    long obase = (((long)b * COUT + o0) * H_ + (h0 + hl)) * W_ + w0;
    const float* vp = v + o0 * VSTRIDE;   // block-uniform -> scalar loads
#pragma unroll
    for (int oi = 0; oi < O_TILE; ++oi) {
        f4 acc = (f4)0.0f;
#pragma unroll
        for (int g = 0; g < G_; ++g) {
            const int gj = g - (g / 3) * 3;
            const float vv = vp[oi * VSTRIDE + g];
            float s0, s1, s2, s3;
            if (gj == 0)      { s0 = sa[g].x; s1 = sa[g].y; s2 = sa[g].z; s3 = sa[g].w; }
            else if (gj == 1) { s0 = sa[g].y; s1 = sa[g].z; s2 = sa[g].w; s3 = sbv[g].x; }
            else              { s0 = sa[g].z; s1 = sa[g].w; s2 = sbv[g].x; s3 = sbv[g].y; }
            acc.x += vv * s0;
            acc.y += vv * s1;
            acc.z += vv * s2;
            acc.w += vv * s3;
        }
        // out is touch-once -> nontemporal; each wave's store = 1 KiB contiguous
        __builtin_nontemporal_store(acc, (f4*)(out + obase + (long)oi * HW_));
    }
}

// ---------------------------------------------------------------------------
extern "C" void kernel_launch(void* const* d_in, const int* in_sizes, int n_in,
                              void* d_out, int out_size, void* d_ws, size_t ws_size,
                              hipStream_t stream) {
    const float* x    = (const float*)d_in[0];   // (32,256,64,64) fp32
    const float* w_pw = (const float*)d_in[1];   // (512,512) fp32
    float* out = (float*)d_out;                  // (32,512,64,64) fp32

    // workspace layout: v[512][16] at 0 (32 KiB exactly), padded s' at 32 KiB
    // (32*9*4488 floats = 5.17 MiB)
    float* v = (float*)d_ws;
    float* s = (float*)((char*)d_ws + 32768);

    // A: w reduction -> v[512][16]
    reduce_w_kernel<<<COUT, 64, 0, stream>>>(w_pw, v);

    // B: x group sum -> padded s' (+ 288 halo-zeroing blocks)
    group_sum_kernel<<<NMAIN + B_ * G_, 256, 0, stream>>>(x, s);

    // C: main shifted pointwise, LDS-free, O_TILE=32
    shift_pw_kernel<<<B_ * (H_ / H_TILE) * (COUT / O_TILE), 256, 0, stream>>>(s, v, out);
}